// Round 5
// baseline (42.320 us; speedup 1.0000x reference)
//
#include <hip/hip_runtime.h>
#include <hip/hip_bf16.h>

#define MDIM 16384
#define NDIM 1024
#define KDIM 512
// fast-path GEMM tile (3-stage pipeline)
#define BM 128
#define BN 256
#define BK 64
#define KTILES (KDIM / BK)   // 8

typedef __attribute__((ext_vector_type(8))) short bf16x8;
typedef __attribute__((ext_vector_type(4))) float f32x4;

__device__ __forceinline__ short f2bf(float f) {
    union { float f; unsigned u; } v; v.f = f;
    unsigned r = v.u + 0x7fff + ((v.u >> 16) & 1);   // RNE truncate to bf16
    return (short)(r >> 16);
}

__device__ __forceinline__ bf16x8 cvt8(float4 a, float4 b) {
    bf16x8 o;
    o[0] = f2bf(a.x); o[1] = f2bf(a.y); o[2] = f2bf(a.z); o[3] = f2bf(a.w);
    o[4] = f2bf(b.x); o[5] = f2bf(b.y); o[6] = f2bf(b.z); o[7] = f2bf(b.w);
    return o;
}

__device__ __forceinline__ void gload_lds16(const void* g, void* l) {
    __builtin_amdgcn_global_load_lds(
        (const __attribute__((address_space(1))) void*)g,
        (__attribute__((address_space(3))) void*)l, 16, 0, 0);
}

// ---------- fused fp32->bf16 convert + sum-of-squares (one wave per row) ----------
__global__ __launch_bounds__(256) void convert_sumsq(
        const float* __restrict__ X, const float* __restrict__ P,
        short* __restrict__ Xbf, short* __restrict__ Pbf,
        float* __restrict__ xsq, float* __restrict__ psq) {
    int wave = (blockIdx.x * blockDim.x + threadIdx.x) >> 6;
    int lane = threadIdx.x & 63;
    const float* src; short* dstb; float* dsts; int row;
    if (wave < MDIM) { src = X; dstb = Xbf; dsts = xsq; row = wave; }
    else             { src = P; dstb = Pbf; dsts = psq; row = wave - MDIM; }
    const float4* r4 = (const float4*)(src + (size_t)row * KDIM) + lane * 2;
    float4 a = r4[0], b = r4[1];
    *(bf16x8*)(dstb + (size_t)row * KDIM + lane * 8) = cvt8(a, b);
    float s = a.x*a.x + a.y*a.y + a.z*a.z + a.w*a.w
            + b.x*b.x + b.y*b.y + b.z*b.z + b.w*b.w;
    #pragma unroll
    for (int off = 32; off; off >>= 1) s += __shfl_down(s, off, 64);
    if (lane == 0) dsts[row] = s;
}

// ---------- fast path: 128x256 tile, 3-buffer 2-deep counted-vmcnt GEMM ----------
// T3+T4 with real counted waits: stage(t+2) issued during tile t; at the tile
// boundary wait vmcnt(6) -> only stage(t+1)'s 6 loads drain while stage(t+2)'s
// 6 remain in flight (a full tile ~2000cyc of cover per prefetch).
// Race analysis:
//  - buffer (t+2)%3 was last READ in tile t-1; all its ds_reads are consumed
//    by MFMAs before the t-1 boundary s_barrier -> retired before any wave
//    can issue stage(t+2) writes (which happen after that barrier).
//  - compute(t) reads buffer t%3, gated by vmcnt(6)+s_barrier at end of t-1:
//    each wave's own stage(t) loads are complete pre-barrier; uniform issue
//    order makes this a cross-wave guarantee.
//  - sched_barrier(0) after each gate stops ds_read hoisting above it (r263).
// LDS content swizzle via pre-XOR'd global source (rule #21), fragment/read
// addressing identical in form to the verified R1-R4 kernels.
__global__ __launch_bounds__(512, 2) void dist_gemm3s(
        const short* __restrict__ Xbf, const short* __restrict__ Pbf,
        const float* __restrict__ xsq, const float* __restrict__ psq,
        float* __restrict__ out) {
    __shared__ short As[3][BM * BK];   // 3 x 16 KB
    __shared__ short Bs[3][BN * BK];   // 3 x 32 KB   (total 144 KB)

    int tid = threadIdx.x;
    int bid = blockIdx.x;
    // bijective XCD swizzle: nwg = 512, chunks of 64 per XCD.
    // Consecutive swz within a chunk share bm -> 4 N-blocks of one A-panel
    // run concurrently on the same XCD (A fetched once into that L2).
    int swz = (bid & 7) * 64 + (bid >> 3);
    int bn = swz & 3, bm = swz >> 2;
    int row0 = bm * BM, col0 = bn * BN;

    int lane = tid & 63, wid = tid >> 6;
    int wr = wid >> 2, wc = wid & 3;         // 2(M) x 4(N) wave grid, 64x64/wave

    f32x4 acc[4][4] = {};

    const short* Ab = Xbf + (size_t)row0 * KDIM;
    const short* Bb = Pbf + (size_t)col0 * KDIM;

    // stage A-tile (2 loads/thread) and B-tile (4 loads/thread) of K-tile kt
    auto stageA = [&](int sel, int kt) {
        #pragma unroll
        for (int s = 0; s < 2; ++s) {
            int c = s * 512 + tid;               // chunk 0..1023
            int row = c >> 3;                    // 0..127
            int g16 = (c & 7) ^ (row & 7);       // pre-swizzled source slot
            const char* ga = (const char*)(Ab + (size_t)row * KDIM)
                             + (size_t)kt * (BK * 2) + g16 * 16;
            gload_lds16(ga, (char*)&As[sel][0] + s * 8192 + wid * 1024);
        }
    };
    auto stageB = [&](int sel, int kt) {
        #pragma unroll
        for (int s = 0; s < 4; ++s) {
            int c = s * 512 + tid;               // chunk 0..2047
            int row = c >> 3;                    // 0..255
            int g16 = (c & 7) ^ (row & 7);
            const char* gb = (const char*)(Bb + (size_t)row * KDIM)
                             + (size_t)kt * (BK * 2) + g16 * 16;
            gload_lds16(gb, (char*)&Bs[sel][0] + s * 8192 + wid * 1024);
        }
    };

    auto lds_off = [&](int row, int kb) {
        return (row * (BK * 2) + kb) ^ ((row & 7) << 4);
    };

    auto compute = [&](int sel) {
        const char* aB = (const char*)&As[sel][0];
        const char* bB = (const char*)&Bs[sel][0];
        #pragma unroll
        for (int ks = 0; ks < 2; ++ks) {
            int kb = ks * 64 + ((lane >> 4) * 16);
            bf16x8 af[4], bfr[4];
            #pragma unroll
            for (int m = 0; m < 4; ++m)
                af[m] = *(const bf16x8*)(aB +
                    lds_off(wr * 64 + m * 16 + (lane & 15), kb));
            #pragma unroll
            for (int n = 0; n < 4; ++n)
                bfr[n] = *(const bf16x8*)(bB +
                    lds_off(wc * 64 + n * 16 + (lane & 15), kb));
            __builtin_amdgcn_s_setprio(1);
            #pragma unroll
            for (int m = 0; m < 4; ++m)
                #pragma unroll
                for (int n = 0; n < 4; ++n)
                    acc[m][n] = __builtin_amdgcn_mfma_f32_16x16x32_bf16(
                        af[m], bfr[n], acc[m][n], 0, 0, 0);
            __builtin_amdgcn_s_setprio(0);
        }
    };

    // prologue: fill pipeline 2 deep; wait only for tile 0 (vmcnt(6))
    stageA(0, 0); stageB(0, 0);
    stageA(1, 1); stageB(1, 1);
    asm volatile("s_waitcnt vmcnt(6)" ::: "memory");
    __builtin_amdgcn_s_barrier();
    __builtin_amdgcn_sched_barrier(0);

    #pragma unroll
    for (int t = 0; t < KTILES; ++t) {
        if (t + 2 < KTILES) {                    // issue stage(t+2) into dead buffer
            stageA((t + 2) % 3, t + 2);
            stageB((t + 2) % 3, t + 2);
        }
        compute(t % 3);
        if (t < KTILES - 1) {
            if (t < KTILES - 2)
                asm volatile("s_waitcnt vmcnt(6)" ::: "memory");  // counted wait
            else
                asm volatile("s_waitcnt vmcnt(0)" ::: "memory");  // tail drain
            __builtin_amdgcn_s_barrier();
            __builtin_amdgcn_sched_barrier(0);
        }
    }

    // epilogue: C/D layout col = lane&15, row = (lane>>4)*4 + reg  [m89]
    int cr = (lane >> 4) * 4;
    int cc = lane & 15;
    float ps[4];
    #pragma unroll
    for (int n = 0; n < 4; ++n) ps[n] = psq[col0 + wc * 64 + n * 16 + cc];
    #pragma unroll
    for (int m = 0; m < 4; ++m) {
        int grb = row0 + wr * 64 + m * 16 + cr;
        #pragma unroll
        for (int r = 0; r < 4; ++r) {
            float xv = xsq[grb + r];
            size_t ob = (size_t)(grb + r) * NDIM;
            #pragma unroll
            for (int n = 0; n < 4; ++n) {
                int gc = col0 + wc * 64 + n * 16 + cc;
                out[ob + gc] = 2.0f * acc[m][n][r] - xv - ps[n];
            }
        }
    }
}

// ---------- fallback path (round-1 kernels, used if ws too small) ----------
__global__ __launch_bounds__(256) void sumsq_kernel(
        const float* __restrict__ X, const float* __restrict__ P,
        float* __restrict__ xsq, float* __restrict__ psq) {
    int wave = (blockIdx.x * blockDim.x + threadIdx.x) >> 6;
    int lane = threadIdx.x & 63;
    const float* src; float* dst; int row;
    if (wave < MDIM) { src = X; dst = xsq; row = wave; }
    else             { src = P; dst = psq; row = wave - MDIM; }
    const float4* r4 = (const float4*)(src + (size_t)row * KDIM) + lane * 2;
    float4 a = r4[0], b = r4[1];
    float s = a.x*a.x + a.y*a.y + a.z*a.z + a.w*a.w
            + b.x*b.x + b.y*b.y + b.z*b.z + b.w*b.w;
    #pragma unroll
    for (int off = 32; off; off >>= 1) s += __shfl_down(s, off, 64);
    if (lane == 0) dst[row] = s;
}

__global__ __launch_bounds__(256) void dist_gemm(
        const float* __restrict__ X, const float* __restrict__ P,
        const float* __restrict__ xsq, const float* __restrict__ psq,
        float* __restrict__ out) {
    __shared__ short As[128 * BK];
    __shared__ short Bs[128 * BK];
    int tid = threadIdx.x;
    int bid = blockIdx.x;
    int swz = (bid & 7) * 128 + (bid >> 3);
    int bn = swz & 7, bm = swz >> 3;
    int row0 = bm * 128, col0 = bn * 128;
    int lane = tid & 63, wid = tid >> 6;
    int wm = (wid >> 1) * 64, wn = (wid & 1) * 64;
    f32x4 acc[4][4] = {};
    int rbase = tid >> 3;
    int kg = tid & 7;
    const float* Abase = X + (size_t)row0 * KDIM;
    const float* Bbase = P + (size_t)col0 * KDIM;
    for (int kt = 0; kt < KDIM / BK; ++kt) {
        int kofs = kt * BK + kg * 8;
        __syncthreads();
        #pragma unroll
        for (int i = 0; i < 4; ++i) {
            int row = rbase + 32 * i;
            const float4* ga = (const float4*)(Abase + (size_t)row * KDIM + kofs);
            float4 a0 = ga[0], a1 = ga[1];
            const float4* gb = (const float4*)(Bbase + (size_t)row * KDIM + kofs);
            float4 b0 = gb[0], b1 = gb[1];
            int off = (row * (BK * 2) + kg * 16) ^ ((row & 7) << 4);
            *(bf16x8*)((char*)As + off) = cvt8(a0, a1);
            *(bf16x8*)((char*)Bs + off) = cvt8(b0, b1);
        }
        __syncthreads();
        #pragma unroll
        for (int ks = 0; ks < 2; ++ks) {
            bf16x8 af[4], bfr[4];
            int kb = ks * 64 + ((lane >> 4) * 16);
            #pragma unroll
            for (int m = 0; m < 4; ++m) {
                int row = wm + m * 16 + (lane & 15);
                int off = (row * (BK * 2) + kb) ^ ((row & 7) << 4);
                af[m] = *(const bf16x8*)((const char*)As + off);
            }
            #pragma unroll
            for (int n = 0; n < 4; ++n) {
                int row = wn + n * 16 + (lane & 15);
                int off = (row * (BK * 2) + kb) ^ ((row & 7) << 4);
                bfr[n] = *(const bf16x8*)((const char*)Bs + off);
            }
            #pragma unroll
            for (int m = 0; m < 4; ++m)
                #pragma unroll
                for (int n = 0; n < 4; ++n)
                    acc[m][n] = __builtin_amdgcn_mfma_f32_16x16x32_bf16(
                        af[m], bfr[n], acc[m][n], 0, 0, 0);
        }
    }
    int cr = (lane >> 4) * 4;
    int cc = lane & 15;
    #pragma unroll
    for (int n = 0; n < 4; ++n) {
        int gc = col0 + wn + n * 16 + cc;
        float ps = psq[gc];
        #pragma unroll
        for (int m = 0; m < 4; ++m) {
            int grb = row0 + wm + m * 16 + cr;
            #pragma unroll
            for (int r = 0; r < 4; ++r) {
                float v = 2.0f * acc[m][n][r] - xsq[grb + r] - ps;
                out[(size_t)(grb + r) * NDIM + gc] = v;
            }
        }
    }
}

extern "C" void kernel_launch(void* const* d_in, const int* in_sizes, int n_in,
                              void* d_out, int out_size, void* d_ws, size_t ws_size,
                              hipStream_t stream) {
    const float* X = (const float*)d_in[0];
    const float* P = (const float*)d_in[1];
    float* out = (float*)d_out;

    const size_t bf_elems = (size_t)(MDIM + NDIM) * KDIM;      // 8,912,896
    const size_t need = bf_elems * 2 + (size_t)(MDIM + NDIM) * 4;

    if (ws_size >= need) {
        short* Xbf = (short*)d_ws;
        short* Pbf = Xbf + (size_t)MDIM * KDIM;
        float* xsq = (float*)(Xbf + bf_elems);
        float* psq = xsq + MDIM;
        convert_sumsq<<<(MDIM + NDIM) / 4, 256, 0, stream>>>(X, P, Xbf, Pbf, xsq, psq);
        dist_gemm3s<<<(MDIM / BM) * (NDIM / BN), 512, 0, stream>>>(Xbf, Pbf, xsq, psq, out);
    } else {
        float* xsq = (float*)d_ws;
        float* psq = xsq + MDIM;
        sumsq_kernel<<<(MDIM + NDIM) / 4, 256, 0, stream>>>(X, P, xsq, psq);
        dist_gemm<<<(MDIM / 128) * (NDIM / 128), 256, 0, stream>>>(X, P, xsq, psq, out);
    }
}

// Round 6
// 41.096 us; speedup vs baseline: 1.0298x; 1.0298x over previous
//
#include <hip/hip_runtime.h>
#include <hip/hip_bf16.h>

#define MDIM 16384
#define NDIM 1024
#define KDIM 512
// fast-path GEMM tile: 128x128, double-buffered, 2 blocks/CU
#define BM 128
#define BN 128
#define BK 64
#define KTILES (KDIM / BK)   // 8

typedef __attribute__((ext_vector_type(8))) short bf16x8;
typedef __attribute__((ext_vector_type(4))) float f32x4;

__device__ __forceinline__ short f2bf(float f) {
    union { float f; unsigned u; } v; v.f = f;
    unsigned r = v.u + 0x7fff + ((v.u >> 16) & 1);   // RNE truncate to bf16
    return (short)(r >> 16);
}

__device__ __forceinline__ bf16x8 cvt8(float4 a, float4 b) {
    bf16x8 o;
    o[0] = f2bf(a.x); o[1] = f2bf(a.y); o[2] = f2bf(a.z); o[3] = f2bf(a.w);
    o[4] = f2bf(b.x); o[5] = f2bf(b.y); o[6] = f2bf(b.z); o[7] = f2bf(b.w);
    return o;
}

__device__ __forceinline__ void gload_lds16(const void* g, void* l) {
    __builtin_amdgcn_global_load_lds(
        (const __attribute__((address_space(1))) void*)g,
        (__attribute__((address_space(3))) void*)l, 16, 0, 0);
}

// ---------- fused fp32->bf16 convert + sum-of-squares (one wave per row) ----------
__global__ __launch_bounds__(256) void convert_sumsq(
        const float* __restrict__ X, const float* __restrict__ P,
        short* __restrict__ Xbf, short* __restrict__ Pbf,
        float* __restrict__ xsq, float* __restrict__ psq) {
    int wave = (blockIdx.x * blockDim.x + threadIdx.x) >> 6;
    int lane = threadIdx.x & 63;
    const float* src; short* dstb; float* dsts; int row;
    if (wave < MDIM) { src = X; dstb = Xbf; dsts = xsq; row = wave; }
    else             { src = P; dstb = Pbf; dsts = psq; row = wave - MDIM; }
    const float4* r4 = (const float4*)(src + (size_t)row * KDIM) + lane * 2;
    float4 a = r4[0], b = r4[1];
    *(bf16x8*)(dstb + (size_t)row * KDIM + lane * 8) = cvt8(a, b);
    float s = a.x*a.x + a.y*a.y + a.z*a.z + a.w*a.w
            + b.x*b.x + b.y*b.y + b.z*b.z + b.w*b.w;
    #pragma unroll
    for (int off = 32; off; off >>= 1) s += __shfl_down(s, off, 64);
    if (lane == 0) dsts[row] = s;
}

// ---------- fast path: 128x128 dbuf 2-phase GEMM, 2 blocks/CU ----------
// Same verified 2-phase structure as R3 (prefetch next tile before compute,
// one __syncthreads per K-tile), shrunk to 64KB LDS / <=128 VGPR so TWO
// blocks co-reside per CU: block i's 64KB epilogue store overlaps block
// i+1's staging+MFMA on the same CU, hiding the store tail that dominated
// the 1-block/CU variants. Staging via global_load_lds w16 with pre-XOR'd
// source (rule #21); swizzled ds_read addressing verbatim from R1-R5.
__global__ __launch_bounds__(512, 4) void dist_gemm_db(
        const short* __restrict__ Xbf, const short* __restrict__ Pbf,
        const float* __restrict__ xsq, const float* __restrict__ psq,
        float* __restrict__ out) {
    __shared__ short As[2][BM * BK];   // 2 x 16 KB
    __shared__ short Bs[2][BN * BK];   // 2 x 16 KB   (total 64 KB)

    int tid = threadIdx.x;
    int bid = blockIdx.x;
    // bijective XCD swizzle: nwg = 1024, chunks of 128 per XCD.
    // Consecutive swz share bm (8 bn's per bm) -> each A-panel read by 8
    // co-XCD blocks; per-XCD L2 working set = 16 A-panels (2MB) + B (1MB).
    int swz = (bid & 7) * 128 + (bid >> 3);
    int bn = swz & 7, bm = swz >> 3;
    int row0 = bm * BM, col0 = bn * BN;

    int lane = tid & 63, wid = tid >> 6;
    int wr = wid >> 2, wc = wid & 3;     // 2(M) x 4(N) waves; 64x32 per wave

    f32x4 acc[4][2] = {};

    const short* Ab = Xbf + (size_t)row0 * KDIM;
    const short* Bb = Pbf + (size_t)col0 * KDIM;

    // stage one K-tile (A+B) into buffer sel: 2+2 gload16/thread
    auto stage = [&](int sel, int kt) {
        #pragma unroll
        for (int s = 0; s < 2; ++s) {
            int c = s * 512 + tid;               // chunk 0..1023
            int row = c >> 3;                    // 0..127
            int g16 = (c & 7) ^ (row & 7);       // pre-swizzled source slot
            const char* ga = (const char*)(Ab + (size_t)row * KDIM)
                             + (size_t)kt * (BK * 2) + g16 * 16;
            const char* gb = (const char*)(Bb + (size_t)row * KDIM)
                             + (size_t)kt * (BK * 2) + g16 * 16;
            char* la = (char*)&As[sel][0] + s * 8192 + wid * 1024;  // wave-uniform
            char* lb = (char*)&Bs[sel][0] + s * 8192 + wid * 1024;
            gload_lds16(ga, la);
            gload_lds16(gb, lb);
        }
    };

    auto lds_off = [&](int row, int kb) {
        return (row * (BK * 2) + kb) ^ ((row & 7) << 4);
    };

    auto compute = [&](int sel) {
        const char* aB = (const char*)&As[sel][0];
        const char* bB = (const char*)&Bs[sel][0];
        #pragma unroll
        for (int ks = 0; ks < 2; ++ks) {
            int kb = ks * 64 + ((lane >> 4) * 16);
            bf16x8 af[4], bfr[2];
            #pragma unroll
            for (int m = 0; m < 4; ++m)
                af[m] = *(const bf16x8*)(aB +
                    lds_off(wr * 64 + m * 16 + (lane & 15), kb));
            #pragma unroll
            for (int n = 0; n < 2; ++n)
                bfr[n] = *(const bf16x8*)(bB +
                    lds_off(wc * 32 + n * 16 + (lane & 15), kb));
            #pragma unroll
            for (int m = 0; m < 4; ++m)
                #pragma unroll
                for (int n = 0; n < 2; ++n)
                    acc[m][n] = __builtin_amdgcn_mfma_f32_16x16x32_bf16(
                        af[m], bfr[n], acc[m][n], 0, 0, 0);
        }
    };

    // prologue
    stage(0, 0);
    __syncthreads();
    int cur = 0;
    #pragma unroll
    for (int kt = 0; kt < KTILES - 1; ++kt) {
        stage(cur ^ 1, kt + 1);      // issue next-tile loads (in flight)
        compute(cur);                // MFMA on current tile
        __syncthreads();             // drains vmcnt; buf reuse safe
        cur ^= 1;
    }
    compute(cur);

    // epilogue: C/D layout col = lane&15, row = (lane>>4)*4 + reg  [m89]
    int cr = (lane >> 4) * 4;
    int cc = lane & 15;
    float ps[2];
    #pragma unroll
    for (int n = 0; n < 2; ++n) ps[n] = psq[col0 + wc * 32 + n * 16 + cc];
    #pragma unroll
    for (int m = 0; m < 4; ++m) {
        int grb = row0 + wr * 64 + m * 16 + cr;
        #pragma unroll
        for (int r = 0; r < 4; ++r) {
            float xv = xsq[grb + r];
            size_t ob = (size_t)(grb + r) * NDIM;
            #pragma unroll
            for (int n = 0; n < 2; ++n) {
                int gc = col0 + wc * 32 + n * 16 + cc;
                out[ob + gc] = 2.0f * acc[m][n][r] - xv - ps[n];
            }
        }
    }
}

// ---------- fallback path (round-1 kernels, used if ws too small) ----------
__global__ __launch_bounds__(256) void sumsq_kernel(
        const float* __restrict__ X, const float* __restrict__ P,
        float* __restrict__ xsq, float* __restrict__ psq) {
    int wave = (blockIdx.x * blockDim.x + threadIdx.x) >> 6;
    int lane = threadIdx.x & 63;
    const float* src; float* dst; int row;
    if (wave < MDIM) { src = X; dst = xsq; row = wave; }
    else             { src = P; dst = psq; row = wave - MDIM; }
    const float4* r4 = (const float4*)(src + (size_t)row * KDIM) + lane * 2;
    float4 a = r4[0], b = r4[1];
    float s = a.x*a.x + a.y*a.y + a.z*a.z + a.w*a.w
            + b.x*b.x + b.y*b.y + b.z*b.z + b.w*b.w;
    #pragma unroll
    for (int off = 32; off; off >>= 1) s += __shfl_down(s, off, 64);
    if (lane == 0) dst[row] = s;
}

__global__ __launch_bounds__(256) void dist_gemm(
        const float* __restrict__ X, const float* __restrict__ P,
        const float* __restrict__ xsq, const float* __restrict__ psq,
        float* __restrict__ out) {
    __shared__ short As[128 * BK];
    __shared__ short Bs[128 * BK];
    int tid = threadIdx.x;
    int bid = blockIdx.x;
    int swz = (bid & 7) * 128 + (bid >> 3);
    int bn = swz & 7, bm = swz >> 3;
    int row0 = bm * 128, col0 = bn * 128;
    int lane = tid & 63, wid = tid >> 6;
    int wm = (wid >> 1) * 64, wn = (wid & 1) * 64;
    f32x4 acc[4][4] = {};
    int rbase = tid >> 3;
    int kg = tid & 7;
    const float* Abase = X + (size_t)row0 * KDIM;
    const float* Bbase = P + (size_t)col0 * KDIM;
    for (int kt = 0; kt < KDIM / BK; ++kt) {
        int kofs = kt * BK + kg * 8;
        __syncthreads();
        #pragma unroll
        for (int i = 0; i < 4; ++i) {
            int row = rbase + 32 * i;
            const float4* ga = (const float4*)(Abase + (size_t)row * KDIM + kofs);
            float4 a0 = ga[0], a1 = ga[1];
            const float4* gb = (const float4*)(Bbase + (size_t)row * KDIM + kofs);
            float4 b0 = gb[0], b1 = gb[1];
            int off = (row * (BK * 2) + kg * 16) ^ ((row & 7) << 4);
            *(bf16x8*)((char*)As + off) = cvt8(a0, a1);
            *(bf16x8*)((char*)Bs + off) = cvt8(b0, b1);
        }
        __syncthreads();
        #pragma unroll
        for (int ks = 0; ks < 2; ++ks) {
            bf16x8 af[4], bfr[4];
            int kb = ks * 64 + ((lane >> 4) * 16);
            #pragma unroll
            for (int m = 0; m < 4; ++m) {
                int row = wm + m * 16 + (lane & 15);
                int off = (row * (BK * 2) + kb) ^ ((row & 7) << 4);
                af[m] = *(const bf16x8*)((const char*)As + off);
            }
            #pragma unroll
            for (int n = 0; n < 4; ++n) {
                int row = wn + n * 16 + (lane & 15);
                int off = (row * (BK * 2) + kb) ^ ((row & 7) << 4);
                bfr[n] = *(const bf16x8*)((const char*)Bs + off);
            }
            #pragma unroll
            for (int m = 0; m < 4; ++m)
                #pragma unroll
                for (int n = 0; n < 4; ++n)
                    acc[m][n] = __builtin_amdgcn_mfma_f32_16x16x32_bf16(
                        af[m], bfr[n], acc[m][n], 0, 0, 0);
        }
    }
    int cr = (lane >> 4) * 4;
    int cc = lane & 15;
    #pragma unroll
    for (int n = 0; n < 4; ++n) {
        int gc = col0 + wn + n * 16 + cc;
        float ps = psq[gc];
        #pragma unroll
        for (int m = 0; m < 4; ++m) {
            int grb = row0 + wm + m * 16 + cr;
            #pragma unroll
            for (int r = 0; r < 4; ++r) {
                float v = 2.0f * acc[m][n][r] - xsq[grb + r] - ps;
                out[(size_t)(grb + r) * NDIM + gc] = v;
            }
        }
    }
}

extern "C" void kernel_launch(void* const* d_in, const int* in_sizes, int n_in,
                              void* d_out, int out_size, void* d_ws, size_t ws_size,
                              hipStream_t stream) {
    const float* X = (const float*)d_in[0];
    const float* P = (const float*)d_in[1];
    float* out = (float*)d_out;

    const size_t bf_elems = (size_t)(MDIM + NDIM) * KDIM;      // 8,912,896
    const size_t need = bf_elems * 2 + (size_t)(MDIM + NDIM) * 4;

    if (ws_size >= need) {
        short* Xbf = (short*)d_ws;
        short* Pbf = Xbf + (size_t)MDIM * KDIM;
        float* xsq = (float*)(Xbf + bf_elems);
        float* psq = xsq + MDIM;
        convert_sumsq<<<(MDIM + NDIM) / 4, 256, 0, stream>>>(X, P, Xbf, Pbf, xsq, psq);
        dist_gemm_db<<<(MDIM / BM) * (NDIM / BN), 512, 0, stream>>>(Xbf, Pbf, xsq, psq, out);
    } else {
        float* xsq = (float*)d_ws;
        float* psq = xsq + MDIM;
        sumsq_kernel<<<(MDIM + NDIM) / 4, 256, 0, stream>>>(X, P, xsq, psq);
        dist_gemm<<<(MDIM / 128) * (NDIM / 128), 256, 0, stream>>>(X, P, xsq, psq, out);
    }
}